// Round 8
// baseline (403.148 us; speedup 1.0000x reference)
//
#include <hip/hip_runtime.h>
#include <stdint.h>
#include <stddef.h>

// Problem constants
#define B_ 4
#define L_ 8192
#define D_ 512
#define M_ (B_*L_)      // 32768 rows
#define K_ 512
#define CHUNK 64
#define NC (L_/CHUNK)   // 128 chunks per sequence

typedef _Float16 f16;
typedef f16 f16x2 __attribute__((ext_vector_type(2)));
typedef f16 f16x8 __attribute__((ext_vector_type(8)));
typedef float f32x4 __attribute__((ext_vector_type(4)));

// ---------------- async global->LDS (16B/lane) ----------------
__device__ __forceinline__ void async16(const void* g, void* l) {
  __builtin_amdgcn_global_load_lds(
      (const __attribute__((address_space(1))) uint32_t*)g,
      (__attribute__((address_space(3))) uint32_t*)l,
      16, 0, 0);
}

// agent-scope (device/cross-XCD visible) load & store for fp32
__device__ __forceinline__ float aload(const float* p) {
  return __hip_atomic_load(p, __ATOMIC_RELAXED, __HIP_MEMORY_SCOPE_AGENT);
}
__device__ __forceinline__ void astore(float* p, float v) {
  __hip_atomic_store(p, v, __ATOMIC_RELAXED, __HIP_MEMORY_SCOPE_AGENT);
}

// ---------------- prep: cvt + pack with baked XOR swizzle (R7, verified) ---
// unit u (16B) -> u ^ (row & 7) within each 128B row-segment.
__global__ __launch_bounds__(256) void prep(const float* __restrict__ x,
                                            const float* __restrict__ Wg,
                                            const float* __restrict__ Wc,
                                            f16* __restrict__ xh,
                                            f16* __restrict__ wp) {
  const int bid = blockIdx.x;
  const int isX = (bid < 8192);
  const int U = (isX ? bid : (bid - 8192)) * 256 + threadIdx.x;  // unit idx
  const int r  = U >> 6;               // row (64 units per 512-f16 row)
  const int w_ = U & 63;
  const int s  = w_ >> 3;
  const int u3 = w_ & 7;
  const int du = (r << 6) + (s << 3) + (u3 ^ (r & 7));
  const float* src;
  if (isX)            src = x + (size_t)U * 8;
  else if (r < 512)   src = Wg + (size_t)r * 512 + w_ * 8;
  else                src = Wc + (size_t)(r - 512) * 512 + w_ * 8;
  float4 v0 = *(const float4*)src;
  float4 v1 = *(const float4*)(src + 4);
  f16x8 o = {(f16)v0.x, (f16)v0.y, (f16)v0.z, (f16)v0.w,
             (f16)v1.x, (f16)v1.y, (f16)v1.z, (f16)v1.w};
  f16* dst = isX ? xh : wp;
  *(f16x8*)(dst + (size_t)du * 8) = o;
}

// ---------------- device-wide barrier (workspace counter) ----------------
// Counter memset to 0 by host each launch; monotonic targets -> no reset.
__device__ __forceinline__ void gbar(int* cnt, int target) {
  __threadfence();                     // release my prior stores
  __syncthreads();
  if (threadIdx.x == 0) {
    atomicAdd(cnt, 1);                 // device-scope by default
    while (__hip_atomic_load(cnt, __ATOMIC_RELAXED, __HIP_MEMORY_SCOPE_AGENT) < target)
      __builtin_amdgcn_s_sleep(8);
  }
  __syncthreads();
  __threadfence();                     // acquire
}

// ---------------- fused GEMM + act + composites + global scan + apply -----
// 256 blocks x 512 thr, guaranteed co-resident (96KB LDS, <=256 regs ->
// 1 block/CU). Block = 128-row stripe (2 chunks), loops 4 bn col-tiles with
// the R7-verified BK=64 zero-conflict core (wave tile 64x32-dual, acc 64
// regs). Packed (a,b) HELD IN REGISTERS (4 x 32 u32) across a device-wide
// barrier; after Hpre is computed globally, h is reconstructed in-register
// and written straight to out. Kills AC (64MB w + 64MB r) and scan_apply.
__global__ __launch_bounds__(512, 2) void fused(
    const f16* __restrict__ Xh, const f16* __restrict__ Wp,
    const float* __restrict__ bg, const float* __restrict__ bc,
    float* __restrict__ cA, float* __restrict__ cB,
    float* __restrict__ Hpre, int* __restrict__ bar,
    float* __restrict__ out) {
  __shared__ __align__(16) f16 sA[2][128 * 64];    // 2 x 16 KB
  __shared__ __align__(16) f16 sBg[2][128 * 64];   // 2 x 16 KB
  __shared__ __align__(16) f16 sBc[2][128 * 64];   // 2 x 16 KB => 96 KB

  const int tid = threadIdx.x;
  const int id = blockIdx.x;           // 0..255
  const int bm = (id & 7) * 32 + (id >> 3);   // XCD-contiguous, 0..255

  const int lane = tid & 63;
  const int w = tid >> 6;              // 0..7
  const int wm = w >> 2, wn = w & 3;   // 2m x 4n over 128x128(dual)
  const int l15 = lane & 15, quad = lane >> 4;

  const int srow = tid >> 3;           // 0..63
  const int sp8 = (tid & 7) * 8;
  const f16* gA  = Xh + (size_t)(bm * 128 + srow) * K_ + sp8;
  const f16* gBg = Wp + (size_t)srow * K_ + sp8;            // + bn*128*K_
  const f16* gBc = Wp + (size_t)(512 + srow) * K_ + sp8;    // + bn*128*K_

  // swizzled frag-read unit offsets (row&7 == l15&7 for all frag rows)
  const int xu0 = (quad ^ (l15 & 7)) * 8;
  const int xu1 = xu0 ^ 32;

  const int c_ = bm * 2 + wm;          // global chunk index 0..511
  uint4 ab[4][4][2];                   // held packed (a,b): [bn][i][j]

#define STAGE(kk, b, bo) { \
    async16(gA + (kk),                   &sA[b][tid * 8]); \
    async16(gA + (size_t)64 * K_ + (kk), &sA[b][tid * 8 + 64 * 64]); \
    async16(gBg + (bo) + (kk),                   &sBg[b][tid * 8]); \
    async16(gBg + (bo) + (size_t)64 * K_ + (kk), &sBg[b][tid * 8 + 64 * 64]); \
    async16(gBc + (bo) + (kk),                   &sBc[b][tid * 8]); \
    async16(gBc + (bo) + (size_t)64 * K_ + (kk), &sBc[b][tid * 8 + 64 * 64]); }

#define COMPUTE(bC) { \
    _Pragma("unroll") \
    for (int k32 = 0; k32 < 2; k32++) { \
      const int xu = k32 ? xu1 : xu0; \
      f16x8 af[4], bgf[2], bcf[2]; \
      _Pragma("unroll") \
      for (int i = 0; i < 4; i++) \
        af[i] = *(const f16x8*)(&sA[bC][(wm * 64 + i * 16 + l15) * 64 + xu]); \
      _Pragma("unroll") \
      for (int j = 0; j < 2; j++) { \
        bgf[j] = *(const f16x8*)(&sBg[bC][(wn * 32 + j * 16 + l15) * 64 + xu]); \
        bcf[j] = *(const f16x8*)(&sBc[bC][(wn * 32 + j * 16 + l15) * 64 + xu]); \
      } \
      _Pragma("unroll") \
      for (int i = 0; i < 4; i++) \
        _Pragma("unroll") \
        for (int j = 0; j < 2; j++) { \
          accG[i][j] = __builtin_amdgcn_mfma_f32_16x16x32_f16(af[i], bgf[j], accG[i][j], 0, 0, 0); \
          accC[i][j] = __builtin_amdgcn_mfma_f32_16x16x32_f16(af[i], bcf[j], accC[i][j], 0, 0, 0); \
        } \
    } }

#pragma unroll
  for (int bn = 0; bn < 4; bn++) {
    const size_t bo = (size_t)bn * 128 * K_;
    f32x4 accG[4][2] = {};
    f32x4 accC[4][2] = {};

    STAGE(0, 0, bo);
    asm volatile("s_waitcnt vmcnt(0)" ::: "memory");
    __builtin_amdgcn_s_barrier();
#pragma unroll
    for (int t = 0; t < 7; t++) {
      const int cb = t & 1, nb = cb ^ 1;
      STAGE((t + 1) * 64, nb, bo);
      COMPUTE(cb);
      asm volatile("s_waitcnt vmcnt(0)" ::: "memory");
      __builtin_amdgcn_s_barrier();
    }
    COMPUTE(1);

    // epilogue: act + pack->ab (held), chunk composites -> cA/cB (agent)
#pragma unroll
    for (int j = 0; j < 2; j++) {
      const int col = bn * 128 + wn * 32 + j * 16 + l15;
      const float bgv = bg[col];
      const float bcv = bc[col];
      float blkP[4], blkQ[4];
#pragma unroll
      for (int i = 0; i < 4; i++) {
        float P = 1.0f, Q = 0.0f;
        uint32_t pk[4];
#pragma unroll
        for (int r = 0; r < 4; r++) {
          float yg = accG[i][j][r] + bgv;
          float gg = 1.0f / (1.0f + __expf(-yg));
          float yc = accC[i][j][r] + bcv;
          yc = fminf(fmaxf(yc, -15.0f), 15.0f);
          float tt = __expf(2.0f * yc);
          float cc = (tt - 1.0f) / (tt + 1.0f);
          f16x2 p;
          p[0] = (f16)(1.0f - gg);
          p[1] = (f16)(gg * cc);
          pk[r] = __builtin_bit_cast(uint32_t, p);
          const float av = (float)p[0];
          const float bv = (float)p[1];
          Q = fmaf(av, Q, bv);
          P *= av;
        }
        ab[bn][i][j] = make_uint4(pk[0], pk[1], pk[2], pk[3]);
        float Pp = __shfl_xor(P, 16);
        float Qp = __shfl_xor(Q, 16);
        float nP = P * Pp;
        float nQ = (quad & 1) ? fmaf(P, Qp, Q) : fmaf(Pp, Q, Qp);
        Pp = __shfl_xor(nP, 32);
        Qp = __shfl_xor(nQ, 32);
        blkP[i] = nP * Pp;
        blkQ[i] = (quad & 2) ? fmaf(nP, Qp, nQ) : fmaf(Pp, nQ, Qp);
      }
      float CP = blkP[0], CQ = blkQ[0];
#pragma unroll
      for (int i = 1; i < 4; i++) {
        CQ = fmaf(blkP[i], CQ, blkQ[i]);
        CP *= blkP[i];
      }
      if (quad == 0) {
        astore(&cA[(size_t)c_ * 512 + col], CP);
        astore(&cB[(size_t)c_ * 512 + col], CQ);
      }
    }
  }
#undef COMPUTE
#undef STAGE

  // ---- device-wide barrier 1: all composites visible ----
  gbar(bar, 256);

  // ---- chunk-prefix scan: blocks 0..3 (2048 chains x 128 steps) ----
  if (id < 4) {
    const int seq = blockIdx.x & 3;    // use raw id 0..3 -> sequence
    const int d = tid;
    float h = 0.0f;
    for (int ch = 0; ch < NC; ch++) {
      const int idx = (seq * NC + ch) * 512 + d;
      astore(&Hpre[idx], h);
      h = fmaf(aload(&cA[idx]), h, aload(&cB[idx]));
    }
  }

  // ---- device-wide barrier 2: Hpre visible ----
  gbar(bar, 512);

  // ---- apply: reconstruct h from held ab, write out directly ----
#pragma unroll
  for (int bn = 0; bn < 4; bn++) {
#pragma unroll
    for (int j = 0; j < 2; j++) {
      const int col = bn * 128 + wn * 32 + j * 16 + l15;
      const float h0 = aload(&Hpre[(size_t)c_ * 512 + col]);
      float iA = 1.0f, iB = 0.0f;      // composite of 16-row blocks < i
#pragma unroll
      for (int i = 0; i < 4; i++) {
        const uint4 pk = ab[bn][i][j];
        const f16x2 q0 = __builtin_bit_cast(f16x2, pk.x);
        const f16x2 q1 = __builtin_bit_cast(f16x2, pk.y);
        const f16x2 q2 = __builtin_bit_cast(f16x2, pk.z);
        const f16x2 q3 = __builtin_bit_cast(f16x2, pk.w);
        const float a0 = (float)q0[0], b0 = (float)q0[1];
        const float a1 = (float)q1[0], b1 = (float)q1[1];
        const float a2 = (float)q2[0], b2 = (float)q2[1];
        const float a3 = (float)q3[0], b3 = (float)q3[1];
        // 4-row segment composite
        float P = a0, Q = b0;
        Q = fmaf(a1, Q, b1); P *= a1;
        Q = fmaf(a2, Q, b2); P *= a2;
        Q = fmaf(a3, Q, b3); P *= a3;
        // inclusive scan over quads (t-order), compose cur o prev
        float sP = P, sQ = Q;
        float tP = __shfl_up(sP, 16), tQ = __shfl_up(sQ, 16);
        if (quad >= 1) { sQ = fmaf(sP, tQ, sQ); sP *= tP; }
        tP = __shfl_up(sP, 32); tQ = __shfl_up(sQ, 32);
        if (quad >= 2) { sQ = fmaf(sP, tQ, sQ); sP *= tP; }
        // exclusive for this quad
        float xP = __shfl_up(sP, 16), xQ = __shfl_up(sQ, 16);
        if (quad == 0) { xP = 1.0f; xQ = 0.0f; }
        // full 16-row block composite (quad 3 inclusive), broadcast
        const float bPv = __shfl(sP, 48 + l15);
        const float bQv = __shfl(sQ, 48 + l15);
        // h entering this thread's 4-row segment
        float h = fmaf(xP, fmaf(iA, h0, iB), xQ);
        const size_t rb = (size_t)(bm * 128 + wm * 64 + i * 16 + quad * 4) * 512 + col;
        h = fmaf(a0, h, b0); out[rb]           = h;
        h = fmaf(a1, h, b1); out[rb + 512]     = h;
        h = fmaf(a2, h, b2); out[rb + 1024]    = h;
        h = fmaf(a3, h, b3); out[rb + 1536]    = h;
        // advance i-composite
        iB = fmaf(bPv, iB, bQv);
        iA *= bPv;
      }
    }
  }
}

// ---------------- launch ----------------
extern "C" void kernel_launch(void* const* d_in, const int* in_sizes, int n_in,
                              void* d_out, int out_size, void* d_ws, size_t ws_size,
                              hipStream_t stream) {
  const float* x  = (const float*)d_in[0];
  const float* Wg = (const float*)d_in[1];
  const float* bg = (const float*)d_in[2];
  const float* Wc = (const float*)d_in[3];
  const float* bc = (const float*)d_in[4];
  float* out = (float*)d_out;

  char* ws = (char*)d_ws;
  // workspace layout (bytes):
  //   [0, 32MB)        xh    f16 x (swizzled units)
  //   [32MB, 33MB)     wp    f16 packed weights (swizzled units)
  //   [33MB, 34MB)     cA    fp32 [512][512]
  //   [34MB, 35MB)     cB
  //   [35MB, 36MB)     Hpre
  //   [36MB, +4B)      bar   global-barrier counter
  f16*   xh = (f16*)(ws);
  f16*   wp = (f16*)(ws + 33554432);
  float* cA = (float*)(ws + 34603008);
  float* cB = (float*)(ws + 35651584);
  float* Hp = (float*)(ws + 36700160);
  int*   bar = (int*)(ws + 37748736);

  hipMemsetAsync(bar, 0, sizeof(int), stream);
  prep<<<8448, 256, 0, stream>>>(x, Wg, Wc, xh, wp);
  fused<<<256, 512, 0, stream>>>(xh, wp, bg, bc, cA, cB, Hp, bar, out);
}

// Round 13
// 211.175 us; speedup vs baseline: 1.9091x; 1.9091x over previous
//
#include <hip/hip_runtime.h>
#include <stdint.h>
#include <stddef.h>

// Problem constants
#define B_ 4
#define L_ 8192
#define D_ 512
#define M_ (B_*L_)      // 32768 rows
#define K_ 512
#define CHUNK 64
#define NC (L_/CHUNK)   // 128 chunks per sequence

typedef _Float16 f16;
typedef f16 f16x2 __attribute__((ext_vector_type(2)));
typedef f16 f16x8 __attribute__((ext_vector_type(8)));
typedef float f32x4 __attribute__((ext_vector_type(4)));

// ---------------- async global->LDS (16B/lane) ----------------
__device__ __forceinline__ void async16(const void* g, void* l) {
  __builtin_amdgcn_global_load_lds(
      (const __attribute__((address_space(1))) uint32_t*)g,
      (__attribute__((address_space(3))) uint32_t*)l,
      16, 0, 0);
}

// ---------------- prep: cvt x -> f16 and pack Wg++Wc, LINEAR layout -------
// 8 floats/thread: 32B read, 16B write. x: 16,777,216 f / 8 = 2,097,152
// threads = 8192 blocks; weights: 65,536 units = 256 blocks.
__global__ __launch_bounds__(256) void prep(const float* __restrict__ x,
                                            const float* __restrict__ Wg,
                                            const float* __restrict__ Wc,
                                            f16* __restrict__ xh,
                                            f16* __restrict__ wp) {
  const int bid = blockIdx.x;
  const int isX = (bid < 8192);
  const int U = (isX ? bid : (bid - 8192)) * 256 + threadIdx.x;  // unit idx
  const float* src;
  f16* dst;
  if (isX)            { src = x + (size_t)U * 8;                     dst = xh; }
  else if (U < 32768) { src = Wg + (size_t)U * 8;                    dst = wp; }
  else                { src = Wc + (size_t)(U - 32768) * 8;          dst = wp; }
  float4 v0 = *(const float4*)src;
  float4 v1 = *(const float4*)(src + 4);
  f16x8 o = {(f16)v0.x, (f16)v0.y, (f16)v0.z, (f16)v0.w,
             (f16)v1.x, (f16)v1.y, (f16)v1.z, (f16)v1.w};
  *(f16x8*)(dst + (size_t)U * 8) = o;
}

// ---------------- fused dual-B GEMM + activations + chunk composites ------
// R4's proven core (69.2us): 128x128 tile, 256 thr, BK=32, double-buffered
// LDS, STAGE(t+1) before COMPUTE(t), one raw s_barrier + vmcnt(0)/K-step.
__global__ __launch_bounds__(256, 2) void gemm_act(
    const f16* __restrict__ Xh, const f16* __restrict__ Wp,
    const float* __restrict__ bg, const float* __restrict__ bc,
    uint32_t* __restrict__ AC,
    float* __restrict__ cA, float* __restrict__ cB) {
  __shared__ __align__(16) f16 sA[2][128 * 32];
  __shared__ __align__(16) f16 sBg[2][128 * 32];
  __shared__ __align__(16) f16 sBc[2][128 * 32];

  const int tid = threadIdx.x;
  const int id = blockIdx.x;           // 0..1023
  const int xcd = id & 7;
  const int slot = id >> 3;            // 0..127
  const int g_ = xcd * 128 + slot;
  const int bm = g_ >> 2;              // 0..255
  const int bn = g_ & 3;               // 0..3 (128-col tiles)

  const int lane = tid & 63;
  const int w = tid >> 6;
  const int wm = w >> 1, wn = w & 1;   // 2x2 wave grid over 128x128
  const int l15 = lane & 15, quad = lane >> 4;

  const int srow = tid >> 2;
  const int spc8 = (tid & 3) * 8;
  const f16* gA  = Xh + (size_t)(bm * 128 + srow) * K_ + spc8;
  const f16* gBg = Wp + (size_t)(bn * 128 + srow) * K_ + spc8;
  const f16* gBc = Wp + (size_t)(512 + bn * 128 + srow) * K_ + spc8;

  f32x4 accG[4][4] = {};
  f32x4 accC[4][4] = {};

#define STAGE(kk, b) { \
    async16(gA + (kk),  &sA[b][tid * 8]); \
    async16(gA + (size_t)64 * K_ + (kk),  &sA[b][tid * 8 + 64 * 32]); \
    async16(gBg + (kk), &sBg[b][tid * 8]); \
    async16(gBg + (size_t)64 * K_ + (kk), &sBg[b][tid * 8 + 64 * 32]); \
    async16(gBc + (kk), &sBc[b][tid * 8]); \
    async16(gBc + (size_t)64 * K_ + (kk), &sBc[b][tid * 8 + 64 * 32]); }

#define COMPUTE(bC) { \
    f16x8 af[4], bgf[4], bcf[4]; \
    _Pragma("unroll") \
    for (int i = 0; i < 4; i++) \
      af[i] = *(const f16x8*)(&sA[bC][(wm * 64 + i * 16 + l15) * 32 + quad * 8]); \
    _Pragma("unroll") \
    for (int j = 0; j < 4; j++) { \
      bgf[j] = *(const f16x8*)(&sBg[bC][(wn * 64 + j * 16 + l15) * 32 + quad * 8]); \
      bcf[j] = *(const f16x8*)(&sBc[bC][(wn * 64 + j * 16 + l15) * 32 + quad * 8]); \
    } \
    _Pragma("unroll") \
    for (int i = 0; i < 4; i++) \
      _Pragma("unroll") \
      for (int j = 0; j < 4; j++) { \
        accG[i][j] = __builtin_amdgcn_mfma_f32_16x16x32_f16(af[i], bgf[j], accG[i][j], 0, 0, 0); \
        accC[i][j] = __builtin_amdgcn_mfma_f32_16x16x32_f16(af[i], bcf[j], accC[i][j], 0, 0, 0); \
      } }

  STAGE(0, 0);
  asm volatile("s_waitcnt vmcnt(0)" ::: "memory");
  __builtin_amdgcn_s_barrier();

#pragma unroll
  for (int t = 0; t < 15; t++) {
    const int c = t & 1, n = c ^ 1;
    STAGE((t + 1) * 32, n);
    COMPUTE(c);
    asm volatile("s_waitcnt vmcnt(0)" ::: "memory");
    __builtin_amdgcn_s_barrier();
  }
  COMPUTE(1);                          // K-tile 15
#undef COMPUTE
#undef STAGE

  // Epilogue: sigmoid/tanh, pack (a,b) f16x2 -> AC, and per-chunk (P,Q).
  const int c = bm * 2 + wm;           // global chunk index 0..511
#pragma unroll
  for (int j = 0; j < 4; j++) {
    const int col = bn * 128 + wn * 64 + j * 16 + l15;   // 0..511
    const float bgv = bg[col];
    const float bcv = bc[col];
    float blkP[4], blkQ[4];
#pragma unroll
    for (int i = 0; i < 4; i++) {
      const int mrow = bm * 128 + wm * 64 + i * 16 + quad * 4;
      float P = 1.0f, Q = 0.0f;
#pragma unroll
      for (int r = 0; r < 4; r++) {
        float yg = accG[i][j][r] + bgv;
        float gg = 1.0f / (1.0f + __expf(-yg));        // sigmoid
        float yc = accC[i][j][r] + bcv;
        yc = fminf(fmaxf(yc, -15.0f), 15.0f);
        float t = __expf(2.0f * yc);
        float cc = (t - 1.0f) / (t + 1.0f);            // tanh
        f16x2 p;
        p[0] = (f16)(1.0f - gg);                        // a
        p[1] = (f16)(gg * cc);                          // b
        *(f16x2*)&AC[(size_t)(mrow + r) * 512 + col] = p;
        const float av = (float)p[0];
        const float bv = (float)p[1];
        Q = fmaf(av, Q, bv);
        P *= av;
      }
      float Pp = __shfl_xor(P, 16);
      float Qp = __shfl_xor(Q, 16);
      float nP = P * Pp;
      float nQ = (quad & 1) ? fmaf(P, Qp, Q) : fmaf(Pp, Q, Qp);
      Pp = __shfl_xor(nP, 32);
      Qp = __shfl_xor(nQ, 32);
      blkP[i] = nP * Pp;
      blkQ[i] = (quad & 2) ? fmaf(nP, Qp, nQ) : fmaf(Pp, nQ, Qp);
    }
    float CP = blkP[0], CQ = blkQ[0];
#pragma unroll
    for (int i = 1; i < 4; i++) {
      CQ = fmaf(blkP[i], CQ, blkQ[i]);
      CP *= blkP[i];
    }
    if (quad == 0) {
      cA[(size_t)c * 512 + col] = CP;
      cB[(size_t)c * 512 + col] = CQ;
    }
  }
}

// ---------------- scan pass 2: prefix over chunks -> Hpre ----------------
// 2048 independent (b,d) chains x 128 steps over L2-resident cA/cB.
__global__ __launch_bounds__(64) void scan_chunks(
    const float* __restrict__ cA, const float* __restrict__ cB,
    float* __restrict__ Hpre) {
  const int b = blockIdx.x >> 3;
  const int d = ((blockIdx.x & 7) << 6) + threadIdx.x;
  float h = 0.0f;
#pragma unroll 8
  for (int ch = 0; ch < NC; ch++) {
    const int idx = (b * NC + ch) * 512 + d;
    Hpre[idx] = h;
    h = fmaf(cA[idx], h, cB[idx]);
  }
}

// ---------------- scan pass 3: pure-stream apply (no prefix redo) --------
// 512 blocks x 256 thr, 2 cols/thread; deep unroll for load pipelining.
// AC is L3-resident (written last dispatch); out streams to HBM.
__global__ __launch_bounds__(256) void scan_apply(
    const uint32_t* __restrict__ AC, const float* __restrict__ Hpre,
    float* __restrict__ out) {
  const int blk = blockIdx.x;          // 0..511 = b*NC + ch
  const int d0 = threadIdx.x * 2;
  float2 h = *(const float2*)&Hpre[blk * 512 + d0];
  const size_t base = (size_t)blk * CHUNK * 512 + d0;
#pragma unroll 16
  for (int t = 0; t < CHUNK; t++) {
    const size_t i = base + (size_t)t * 512;
    uint2 v = *(const uint2*)&AC[i];
    f16x2 p0 = __builtin_bit_cast(f16x2, v.x);
    f16x2 p1 = __builtin_bit_cast(f16x2, v.y);
    h.x = fmaf((float)p0[0], h.x, (float)p0[1]);
    h.y = fmaf((float)p1[0], h.y, (float)p1[1]);
    *(float2*)&out[i] = h;
  }
}

// ---------------- launch ----------------
extern "C" void kernel_launch(void* const* d_in, const int* in_sizes, int n_in,
                              void* d_out, int out_size, void* d_ws, size_t ws_size,
                              hipStream_t stream) {
  const float* x  = (const float*)d_in[0];
  const float* Wg = (const float*)d_in[1];
  const float* bg = (const float*)d_in[2];
  const float* Wc = (const float*)d_in[3];
  const float* bc = (const float*)d_in[4];
  float* out = (float*)d_out;

  char* ws = (char*)d_ws;
  // workspace layout (bytes):
  //   [0, 32MB)      xh   f16 x
  //   [32MB, 33MB)   wp   f16 packed weights [1024][512]
  //   [33MB, 97MB)   AC   u32 packed (a,b) f16x2 [32768][512]
  //   [97MB..100MB)  cA, cB, Hpre fp32 (1MB each)
  f16*      xh = (f16*)(ws);
  f16*      wp = (f16*)(ws + 33554432);
  uint32_t* AC = (uint32_t*)(ws + 34603008);
  float*    cA = (float*)(ws + 101711872);
  float*    cB = (float*)(ws + 102760448);
  float*    Hp = (float*)(ws + 103809024);

  prep<<<8448, 256, 0, stream>>>(x, Wg, Wc, xh, wp);
  gemm_act<<<(M_ / 128) * 4, 256, 0, stream>>>(xh, wp, bg, bc, AC, cA, cB);
  scan_chunks<<<32, 64, 0, stream>>>(cA, cB, Hp);
  scan_apply<<<B_ * NC, 256, 0, stream>>>(AC, Hp, out);
}